// Round 1
// baseline (125.465 us; speedup 1.0000x reference)
//
#include <hip/hip_runtime.h>

#define LN_EPS 1e-5f

constexpr int Bn = 4, Nn = 256, Dn = 256, Hn = 256;

// ---------------------------------------------------------------------------
// Kernel 1: aA[m,h] = sum_d x[m,d]*Wg[d,h] + bg[h]   (half=0)
//           bB[m,h] = sum_d x[m,d]*Wg[D+d,h]         (half=1)
// m = b*N+i flattened (1024 rows). 8-row tiles, thread = h column.
// ---------------------------------------------------------------------------
__global__ __launch_bounds__(256) void gemm_ab_kernel(
    const float* __restrict__ x, const float* __restrict__ Wg,
    const float* __restrict__ bg, float* __restrict__ aA, float* __restrict__ bB)
{
    int mt = blockIdx.x;     // 0..127
    int half = blockIdx.y;   // 0 -> a-part, 1 -> b-part
    int m0 = mt * 8;
    int t = threadIdx.x;
    __shared__ float xs[8][256];
    const float4* xsrc = reinterpret_cast<const float4*>(x + m0 * Dn);
    float4* xdst = reinterpret_cast<float4*>(&xs[0][0]);
    for (int k = t; k < 512; k += 256) xdst[k] = xsrc[k];
    __syncthreads();
    int h = t;
    const float* W = Wg + (half ? Dn * Hn : 0) + h;
    float acc[8];
    float binit = half ? 0.0f : bg[h];
#pragma unroll
    for (int mm = 0; mm < 8; ++mm) acc[mm] = binit;
    for (int d = 0; d < 256; d += 4) {
        float w0 = W[(d + 0) * Hn];
        float w1 = W[(d + 1) * Hn];
        float w2 = W[(d + 2) * Hn];
        float w3 = W[(d + 3) * Hn];
#pragma unroll
        for (int mm = 0; mm < 8; ++mm) {
            float4 xv = *reinterpret_cast<const float4*>(&xs[mm][d]);
            acc[mm] = fmaf(xv.x, w0, acc[mm]);
            acc[mm] = fmaf(xv.y, w1, acc[mm]);
            acc[mm] = fmaf(xv.z, w2, acc[mm]);
            acc[mm] = fmaf(xv.w, w3, acc[mm]);
        }
    }
    float* outp = half ? bB : aA;
#pragma unroll
    for (int mm = 0; mm < 8; ++mm) outp[(m0 + mm) * Hn + h] = acc[mm];
}

// ---------------------------------------------------------------------------
// Kernel 2: the fused pair block. Block = (b, 4-row i-tile), 512 threads.
// Phase 1 (thread = j, two i-rows per thread): per-row LN stats in registers.
// Phase 2 (thread = h, two i-rows per thread): coalesced weighted accumulate:
//   part[b,i,h] = sum_j (inv_ij * relu(A_i[h]+b_j[h]) - m_ij*inv_ij)
// LayerNorm affinity: r[b,h] = gamma[h]*sum_i part[b,i,h] + N^2*beta[h].
// ---------------------------------------------------------------------------
__global__ __launch_bounds__(512) void pair_kernel(
    const float* __restrict__ aA, const float* __restrict__ bB,
    float* __restrict__ part)
{
    int b  = blockIdx.x >> 6;
    int i0 = (blockIdx.x & 63) * 4;
    int t = threadIdx.x;
    __shared__ float A[4][256];
    __shared__ float2 invd[4][256];   // (inv, -m*inv) per (i-row, j)

    for (int k = t; k < 1024; k += 512)
        A[k >> 8][k & 255] = aA[(b * Nn + i0 + (k >> 8)) * Hn + (k & 255)];
    __syncthreads();

    int j = t & 255;
    int g = t >> 8;          // wave-uniform (waves 0-3: g=0, waves 4-7: g=1)

    // ---- phase 1: row stats for i-rows {2g, 2g+1} ----
    {
        float s0 = 0.f, s1 = 0.f, q0 = 0.f, q1 = 0.f;
        const float* brow = bB + (b * Nn + j) * Hn;
        const float* A0 = A[2 * g];
        const float* A1 = A[2 * g + 1];
#pragma unroll 2
        for (int h = 0; h < 256; h += 4) {
            float4 bb = *reinterpret_cast<const float4*>(brow + h);
            float4 a0 = *reinterpret_cast<const float4*>(A0 + h);
            float4 a1 = *reinterpret_cast<const float4*>(A1 + h);
            float v;
            v = fmaxf(a0.x + bb.x, 0.f); s0 += v; q0 = fmaf(v, v, q0);
            v = fmaxf(a0.y + bb.y, 0.f); s0 += v; q0 = fmaf(v, v, q0);
            v = fmaxf(a0.z + bb.z, 0.f); s0 += v; q0 = fmaf(v, v, q0);
            v = fmaxf(a0.w + bb.w, 0.f); s0 += v; q0 = fmaf(v, v, q0);
            v = fmaxf(a1.x + bb.x, 0.f); s1 += v; q1 = fmaf(v, v, q1);
            v = fmaxf(a1.y + bb.y, 0.f); s1 += v; q1 = fmaf(v, v, q1);
            v = fmaxf(a1.z + bb.z, 0.f); s1 += v; q1 = fmaf(v, v, q1);
            v = fmaxf(a1.w + bb.w, 0.f); s1 += v; q1 = fmaf(v, v, q1);
        }
        float m0 = s0 * (1.f / 256.f);
        float m1 = s1 * (1.f / 256.f);
        float inv0 = rsqrtf(q0 * (1.f / 256.f) - m0 * m0 + LN_EPS);
        float inv1 = rsqrtf(q1 * (1.f / 256.f) - m1 * m1 + LN_EPS);
        invd[2 * g][j]     = make_float2(inv0, -m0 * inv0);
        invd[2 * g + 1][j] = make_float2(inv1, -m1 * inv1);
    }
    __syncthreads();

    // ---- phase 2: weighted accumulation, coalesced over h ----
    int h = t & 255;
    float a0 = A[2 * g][h];
    float a1 = A[2 * g + 1][h];
    float acc0 = 0.f, acc1 = 0.f;
    const float* bcol = bB + b * Nn * Hn + h;
#pragma unroll 4
    for (int j2 = 0; j2 < 256; ++j2) {
        float bb = bcol[j2 * Hn];
        float2 id0 = invd[2 * g][j2];
        float2 id1 = invd[2 * g + 1][j2];
        float v0 = fmaxf(a0 + bb, 0.f);
        float v1 = fmaxf(a1 + bb, 0.f);
        acc0 += fmaf(id0.x, v0, id0.y);
        acc1 += fmaf(id1.x, v1, id1.y);
    }
    part[(b * Nn + i0 + 2 * g) * Hn + h]     = acc0;
    part[(b * Nn + i0 + 2 * g + 1) * Hn + h] = acc1;
}

// ---------------------------------------------------------------------------
// Kernel 3: per-batch finish. 4 blocks x 1024 threads (h = t&255, q = t>>8).
//   r[h]  = g_gamma[h]*sum_i part[b,i,h] + N^2*g_beta[h]
//   y[h]  = relu(sum_k r[k]*Wf[k,h] + bf[h])
//   rel[h]= LN(y) with f_gamma/f_beta
// ---------------------------------------------------------------------------
__global__ __launch_bounds__(1024) void finish_kernel(
    const float* __restrict__ part,
    const float* __restrict__ gg, const float* __restrict__ gb,
    const float* __restrict__ Wf, const float* __restrict__ bfv,
    const float* __restrict__ fg, const float* __restrict__ fb,
    float* __restrict__ rel)
{
    int b = blockIdx.x;
    int t = threadIdx.x;
    int h = t & 255;
    int q = t >> 8;          // 0..3, wave-uniform

    __shared__ float psum[4][256];
    __shared__ float rs[256];
    __shared__ float ysum[4][256];
    __shared__ float pS[16], pQ[16];

    // partial i-reduction of part
    float s = 0.f;
    const float* p = part + (b * Nn + q * 64) * Hn + h;
#pragma unroll 4
    for (int i = 0; i < 64; ++i) s += p[i * Hn];
    psum[q][h] = s;
    __syncthreads();

    if (q == 0) {
        float rsum = psum[0][h] + psum[1][h] + psum[2][h] + psum[3][h];
        rs[h] = gg[h] * rsum + 65536.0f * gb[h];
    }
    __syncthreads();

    // GEMV partial: k in [q*64, q*64+64)
    float y = 0.f;
    const float* Wcol = Wf + (q * 64) * Hn + h;
#pragma unroll 4
    for (int k = 0; k < 64; ++k) y = fmaf(rs[q * 64 + k], Wcol[k * Hn], y);
    ysum[q][h] = y;
    __syncthreads();

    // all 1024 threads compute v redundantly (same per h across q)
    float v = fmaxf(ysum[0][h] + ysum[1][h] + ysum[2][h] + ysum[3][h] + bfv[h], 0.f);

    // block LN over the 256 distinct h values (each appears 4x; divide by 1024)
    float sv = v, qv = v * v;
#pragma unroll
    for (int off = 32; off >= 1; off >>= 1) {
        sv += __shfl_xor(sv, off, 64);
        qv += __shfl_xor(qv, off, 64);
    }
    int wid = t >> 6, lane = t & 63;
    if (lane == 0) { pS[wid] = sv; pQ[wid] = qv; }
    __syncthreads();
    float S = 0.f, Q = 0.f;
#pragma unroll
    for (int w = 0; w < 16; ++w) { S += pS[w]; Q += pQ[w]; }
    float m = S * (1.f / 1024.f);
    float var = Q * (1.f / 1024.f) - m * m;
    float inv = rsqrtf(var + LN_EPS);

    if (q == 0)
        rel[b * Hn + h] = (v - m) * inv * fg[h] + fb[h];
}

// ---------------------------------------------------------------------------
// Kernel 4: out[b,n,d] = rel[b,d] + x[b,n,d], float4-vectorized.
// ---------------------------------------------------------------------------
__global__ __launch_bounds__(256) void add_kernel(
    const float* __restrict__ rel, const float* __restrict__ x,
    float* __restrict__ out)
{
    int idx = blockIdx.x * blockDim.x + threadIdx.x;   // float4 units, 65536 total
    int b = idx >> 14;                                 // / (256*256/4)
    int d4 = idx & 63;
    float4 r4 = reinterpret_cast<const float4*>(rel)[b * 64 + d4];
    float4 x4 = reinterpret_cast<const float4*>(x)[idx];
    float4 o;
    o.x = r4.x + x4.x;
    o.y = r4.y + x4.y;
    o.z = r4.z + x4.z;
    o.w = r4.w + x4.w;
    reinterpret_cast<float4*>(out)[idx] = o;
}

// ---------------------------------------------------------------------------
extern "C" void kernel_launch(void* const* d_in, const int* in_sizes, int n_in,
                              void* d_out, int out_size, void* d_ws, size_t ws_size,
                              hipStream_t stream)
{
    const float* x   = (const float*)d_in[0];
    const float* Wg  = (const float*)d_in[1];
    const float* bg  = (const float*)d_in[2];
    const float* gg  = (const float*)d_in[3];
    const float* gb  = (const float*)d_in[4];
    const float* Wf  = (const float*)d_in[5];
    const float* bfv = (const float*)d_in[6];
    const float* fg  = (const float*)d_in[7];
    const float* fb  = (const float*)d_in[8];
    float* out = (float*)d_out;

    float* ws   = (float*)d_ws;
    float* aA   = ws;                 // 1024*256
    float* bB   = ws + 262144;        // 1024*256
    float* part = ws + 524288;        // 1024*256
    float* rel  = ws + 786432;        // 4*256

    gemm_ab_kernel<<<dim3(128, 2), 256, 0, stream>>>(x, Wg, bg, aA, bB);
    pair_kernel<<<256, 512, 0, stream>>>(aA, bB, part);
    finish_kernel<<<4, 1024, 0, stream>>>(part, gg, gb, Wf, bfv, fg, fb, rel);
    add_kernel<<<256, 256, 0, stream>>>(rel, x, out);
}